// Round 3
// baseline (898.906 us; speedup 1.0000x reference)
//
#include <hip/hip_runtime.h>
#include <hip/hip_bf16.h>
#include <math.h>

// Problem constants (fixed by the reference)
#define NN 8192     // nodes
#define FF 16       // node features
#define HH 64       // hidden
#define GG 256      // graphs
#define LN_EPS 1e-3f

typedef __bf16 bf16x8 __attribute__((ext_vector_type(8)));
typedef float  floatx4 __attribute__((ext_vector_type(4)));

// ---------------------------------------------------------------------------
// K1: Zt0 = (X @ W0)^T  (bf16, [64][8192]) ; also z = log1p(relu(X[:,0])),
//     segment-max of z via uint atomicMax (z >= 0 so bit-compare == float-compare)
// grid 2048 x 256
__global__ void k1_xw0(const float* __restrict__ X,
                       const float* __restrict__ W0,
                       const int* __restrict__ I,
                       __hip_bfloat16* __restrict__ Zt0,
                       float* __restrict__ zarr,
                       unsigned int* __restrict__ zmax_bits) {
    const int b = blockIdx.x, tid = threadIdx.x;
    const int lane = tid & 63;
    const int i = (b & 127) * 64 + lane;          // node
    const int n = ((b >> 7) << 2) + (tid >> 6);   // output column
    float s = 0.f;
#pragma unroll
    for (int m = 0; m < FF; ++m)
        s += X[i * FF + m] * W0[m * HH + n];
    Zt0[(size_t)n * NN + i] = __float2bfloat16(s);   // coalesced along i

    if (b < 128 && tid < 64) {
        const int ii = b * 64 + lane;
        float z = log1pf(fmaxf(X[ii * FF], 0.f));
        zarr[ii] = z;
        atomicMax(&zmax_bits[I[ii]], __float_as_uint(z));
    }
}

// ---------------------------------------------------------------------------
// K2/K4: P = A[8192,8192](fp32) @ Z[8192,64] (Z transposed, bf16),
//        epilogue: +bias, relu, LayerNorm(gamma,beta), (+resid), -> out fp32
// block = 256 thr (4 waves); tile = 16 rows x 64 cols; wave w owns cols w*16..+15
// grid 512 x 256
__global__ __launch_bounds__(256)
void k_gemm_ln(const float* __restrict__ A,
               const __hip_bfloat16* __restrict__ Zt,
               const float* __restrict__ bias,
               const float* __restrict__ gamma,
               const float* __restrict__ beta,
               const float* __restrict__ resid,   // nullptr for layer 0
               float* __restrict__ out) {
    __shared__ float smem[16][65];
    const int tid  = threadIdx.x;
    const int wave = tid >> 6;
    const int lane = tid & 63;
    const int l16  = lane & 15;
    const int quad = lane >> 4;
    const int row0 = blockIdx.x * 16;

    const float* aptr = A + (size_t)(row0 + l16) * NN + quad * 8;
    const __hip_bfloat16* bptr = Zt + (size_t)(wave * 16 + l16) * NN + quad * 8;

    floatx4 acc = {0.f, 0.f, 0.f, 0.f};
#pragma unroll 8
    for (int k = 0; k < NN; k += 32) {
        const float4 a0 = *reinterpret_cast<const float4*>(aptr + k);
        const float4 a1 = *reinterpret_cast<const float4*>(aptr + k + 4);
        bf16x8 af;
        af[0] = (__bf16)a0.x; af[1] = (__bf16)a0.y;
        af[2] = (__bf16)a0.z; af[3] = (__bf16)a0.w;
        af[4] = (__bf16)a1.x; af[5] = (__bf16)a1.y;
        af[6] = (__bf16)a1.z; af[7] = (__bf16)a1.w;
        const bf16x8 bfr = *reinterpret_cast<const bf16x8*>(bptr + k);
        acc = __builtin_amdgcn_mfma_f32_16x16x32_bf16(af, bfr, acc, 0, 0, 0);
    }

    const int col = wave * 16 + l16;
    const float bv = bias[col];
#pragma unroll
    for (int r = 0; r < 4; ++r) {
        const int rl = quad * 4 + r;               // C/D: row = quad*4 + reg
        smem[rl][col] = fmaxf(acc[r] + bv, 0.f);   // bias + relu
    }
    __syncthreads();

    // LayerNorm over 64 cols; 16 threads per row, 4 elements each
    const int row = tid >> 4;
    const int c0  = (tid & 15) * 4;
    float s = 0.f, ss = 0.f;
#pragma unroll
    for (int j = 0; j < 4; ++j) {
        float v = smem[row][c0 + j];
        s += v; ss += v * v;
    }
#pragma unroll
    for (int m = 1; m < 16; m <<= 1) {
        s  += __shfl_xor(s,  m, 64);
        ss += __shfl_xor(ss, m, 64);
    }
    const float mean = s * (1.f / 64.f);
    const float var  = fmaxf(ss * (1.f / 64.f) - mean * mean, 0.f);
    const float inv  = rsqrtf(var + LN_EPS);
    const size_t grow = (size_t)(row0 + row);
#pragma unroll
    for (int j = 0; j < 4; ++j) {
        const int c = c0 + j;
        float v = (smem[row][c] - mean) * inv * gamma[c] + beta[c];
        if (resid) v += resid[grow * HH + c];
        out[grow * HH + c] = v;
    }
}

// ---------------------------------------------------------------------------
// K3: Zt1 = (h0 @ W1)^T  (bf16 [64][8192])   grid 2048 x 256
__global__ void k3_hw1(const float* __restrict__ h0,
                       const float* __restrict__ W1,
                       __hip_bfloat16* __restrict__ Zt1) {
    const int b = blockIdx.x, tid = threadIdx.x;
    const int lane = tid & 63;
    const int i = (b & 127) * 64 + lane;
    const int n = ((b >> 7) << 2) + (tid >> 6);
    float s = 0.f;
#pragma unroll 8
    for (int m = 0; m < HH; ++m)
        s += h0[(size_t)i * HH + m] * W1[m * HH + n];
    Zt1[(size_t)n * NN + i] = __float2bfloat16(s);
}

// ---------------------------------------------------------------------------
// K5: feat = h@Wf + bf ; attn = sigmoid(h@Wa + ba) ; g[I[i]] += feat*attn
// 4 nodes per block (one wave each).  grid 2048 x 256
__global__ __launch_bounds__(256)
void k5_pool(const float* __restrict__ h,
             const float* __restrict__ Wf, const float* __restrict__ bfv,
             const float* __restrict__ Wa, const float* __restrict__ bav,
             const int* __restrict__ I,
             float* __restrict__ g) {
    __shared__ float hrow[4][64];
    const int w = threadIdx.x >> 6, l = threadIdx.x & 63;
    const int node = blockIdx.x * 4 + w;
    hrow[w][l] = h[(size_t)node * HH + l];
    __syncthreads();
    float sf = bfv[l], sa = bav[l];
#pragma unroll 8
    for (int m = 0; m < HH; ++m) {
        const float hv = hrow[w][m];
        sf += hv * Wf[m * HH + l];
        sa += hv * Wa[m * HH + l];
    }
    const float attn = 1.f / (1.f + expf(-sa));
    atomicAdd(&g[(size_t)I[node] * HH + l], sf * attn);
}

// ---------------------------------------------------------------------------
// K6: zexp = exp(z - zmax[seg]); zsum[seg] += zexp; baryn[seg] += zexp * xyz
// grid 32 x 256
__global__ void k6_bary(const float* __restrict__ X,
                        const int* __restrict__ I,
                        const float* __restrict__ zarr,
                        const float* __restrict__ zmax,
                        float* __restrict__ zsum,
                        float* __restrict__ baryn) {
    const int i = blockIdx.x * 256 + threadIdx.x;
    const int seg = I[i];
    const float ze = expf(zarr[i] - zmax[seg]);
    atomicAdd(&zsum[seg], ze);
    atomicAdd(&baryn[seg * 3 + 0], ze * X[i * FF + 13]);
    atomicAdd(&baryn[seg * 3 + 1], ze * X[i * FF + 14]);
    atomicAdd(&baryn[seg * 3 + 2], ze * X[i * FF + 15]);
}

// ---------------------------------------------------------------------------
// K7: out[gi] = concat(g[gi], baryn[gi]/zsum[gi]) @ Wout + bout   (1 x 256)
// Output dtype: fp32 (reference returns float32 -> d_out is float*)
__global__ void k7_out(const float* __restrict__ g,
                       const float* __restrict__ zsum,
                       const float* __restrict__ baryn,
                       const float* __restrict__ Wout,
                       const float* __restrict__ bout,
                       float* __restrict__ out) {
    const int gi = threadIdx.x;
    float v[67];
#pragma unroll
    for (int k = 0; k < 64; ++k) v[k] = g[gi * HH + k];
    const float zs = zsum[gi];
    const float invz = (zs > 0.f) ? (1.f / zs) : 0.f;
#pragma unroll
    for (int d = 0; d < 3; ++d) v[64 + d] = baryn[gi * 3 + d] * invz;
#pragma unroll
    for (int d = 0; d < 3; ++d) {
        float s = bout[d];
#pragma unroll
        for (int k = 0; k < 67; ++k) s += v[k] * Wout[k * 3 + d];
        out[gi * 3 + d] = s;
    }
}

// ---------------------------------------------------------------------------
extern "C" void kernel_launch(void* const* d_in, const int* in_sizes, int n_in,
                              void* d_out, int out_size, void* d_ws, size_t ws_size,
                              hipStream_t stream) {
    const float* X   = (const float*)d_in[0];
    const float* A   = (const float*)d_in[1];
    const int*   I   = (const int*)d_in[2];
    const float* W0  = (const float*)d_in[3];
    const float* b0  = (const float*)d_in[4];
    const float* g0  = (const float*)d_in[5];
    const float* be0 = (const float*)d_in[6];
    const float* W1  = (const float*)d_in[7];
    const float* b1  = (const float*)d_in[8];
    const float* g1  = (const float*)d_in[9];
    const float* be1 = (const float*)d_in[10];
    const float* Wf  = (const float*)d_in[11];
    const float* bfv = (const float*)d_in[12];
    const float* Wa  = (const float*)d_in[13];
    const float* bav = (const float*)d_in[14];
    const float* Wo  = (const float*)d_in[15];
    const float* bo  = (const float*)d_in[16];

    char* ws = (char*)d_ws;
    __hip_bfloat16* Zt0 = (__hip_bfloat16*)(ws);                    // 1 MiB
    __hip_bfloat16* Zt1 = (__hip_bfloat16*)(ws + (1u << 20));       // 1 MiB
    float* h0   = (float*)(ws + (2u << 20));                        // 2 MiB
    float* h    = (float*)(ws + (4u << 20));                        // 2 MiB
    float* zarr = (float*)(ws + (6u << 20));                        // 32 KiB
    float* accr = (float*)(ws + (6u << 20) + (32u << 10));          // accumulators
    float* g     = accr;                 // 256*64
    float* zmax  = accr + GG * HH;       // 256
    float* zsum  = zmax + GG;            // 256
    float* baryn = zsum + GG;            // 256*3

    hipMemsetAsync(accr, 0, (size_t)(GG * HH + GG + GG + GG * 3) * sizeof(float), stream);

    k1_xw0<<<2048, 256, 0, stream>>>(X, W0, I, Zt0, zarr, (unsigned int*)zmax);
    k_gemm_ln<<<512, 256, 0, stream>>>(A, Zt0, b0, g0, be0, nullptr, h0);
    k3_hw1<<<2048, 256, 0, stream>>>(h0, W1, Zt1);
    k_gemm_ln<<<512, 256, 0, stream>>>(A, Zt1, b1, g1, be1, h0, h);
    k5_pool<<<2048, 256, 0, stream>>>(h, Wf, bfv, Wa, bav, I, g);
    k6_bary<<<32, 256, 0, stream>>>(X, I, zarr, zmax, zsum, baryn);
    k7_out<<<1, 256, 0, stream>>>(g, zsum, baryn, Wo, bo, (float*)d_out);
}

// Round 4
// 602.042 us; speedup vs baseline: 1.4931x; 1.4931x over previous
//
#include <hip/hip_runtime.h>
#include <hip/hip_bf16.h>
#include <math.h>

// Problem constants (fixed by the reference)
#define NN 8192     // nodes
#define FF 16       // node features
#define HH 64       // hidden
#define GG 256      // graphs
#define LN_EPS 1e-3f
#define KSPLIT 8
#define KC (NN / KSPLIT)   // 1024

typedef __bf16 bf16x8 __attribute__((ext_vector_type(8)));
typedef float  floatx4 __attribute__((ext_vector_type(4)));

// ---------------------------------------------------------------------------
// K1: Zt0 = (X @ W0)^T  (bf16, [64][8192]) ; also z = log1p(relu(X[:,0])),
//     segment-max of z via uint atomicMax (z >= 0 so bit-compare == float-compare)
// grid 2048 x 256
__global__ void k1_xw0(const float* __restrict__ X,
                       const float* __restrict__ W0,
                       const int* __restrict__ I,
                       __hip_bfloat16* __restrict__ Zt0,
                       float* __restrict__ zarr,
                       unsigned int* __restrict__ zmax_bits) {
    const int b = blockIdx.x, tid = threadIdx.x;
    const int lane = tid & 63;
    const int i = (b & 127) * 64 + lane;          // node
    const int n = ((b >> 7) << 2) + (tid >> 6);   // output column
    float s = 0.f;
#pragma unroll
    for (int m = 0; m < FF; ++m)
        s += X[i * FF + m] * W0[m * HH + n];
    Zt0[(size_t)n * NN + i] = __float2bfloat16(s);   // coalesced along i

    if (b < 128 && tid < 64) {
        const int ii = b * 64 + lane;
        float z = log1pf(fmaxf(X[ii * FF], 0.f));
        zarr[ii] = z;
        atomicMax(&zmax_bits[I[ii]], __float_as_uint(z));
    }
}

// ---------------------------------------------------------------------------
// K-split MFMA GEMM: C += A[8192,8192](fp32->bf16) @ Z (Zt bf16 [64][8192])
// grid 1024 = 128 rowblocks x 8 ksplit; block 256 thr = 4 waves.
// Block covers 64 rows; wave w rows w*16..+15; 4 independent col-chains (64 cols).
// Partials accumulated into fp32 C via atomicAdd (8 colliders/element).
__global__ __launch_bounds__(256)
void k_gemm_split(const float* __restrict__ A,
                  const __hip_bfloat16* __restrict__ Zt,
                  float* __restrict__ C) {
    const int tid  = threadIdx.x;
    const int wave = tid >> 6;
    const int lane = tid & 63;
    const int l16  = lane & 15;
    const int quad = lane >> 4;
    const int rb   = blockIdx.x & 127;
    const int kb   = blockIdx.x >> 7;
    const int row0 = rb * 64;
    const int k0   = kb * KC;

    const float* aptr = A + (size_t)(row0 + wave * 16 + l16) * NN + k0 + quad * 8;
    const __hip_bfloat16* bp0 = Zt + (size_t)(0 * 16 + l16) * NN + k0 + quad * 8;
    const __hip_bfloat16* bp1 = Zt + (size_t)(1 * 16 + l16) * NN + k0 + quad * 8;
    const __hip_bfloat16* bp2 = Zt + (size_t)(2 * 16 + l16) * NN + k0 + quad * 8;
    const __hip_bfloat16* bp3 = Zt + (size_t)(3 * 16 + l16) * NN + k0 + quad * 8;

    floatx4 acc0 = {0.f,0.f,0.f,0.f}, acc1 = {0.f,0.f,0.f,0.f};
    floatx4 acc2 = {0.f,0.f,0.f,0.f}, acc3 = {0.f,0.f,0.f,0.f};

#pragma unroll 4
    for (int k = 0; k < KC; k += 32) {
        const float4 a0 = *reinterpret_cast<const float4*>(aptr + k);
        const float4 a1 = *reinterpret_cast<const float4*>(aptr + k + 4);
        bf16x8 af;
        af[0] = (__bf16)a0.x; af[1] = (__bf16)a0.y;
        af[2] = (__bf16)a0.z; af[3] = (__bf16)a0.w;
        af[4] = (__bf16)a1.x; af[5] = (__bf16)a1.y;
        af[6] = (__bf16)a1.z; af[7] = (__bf16)a1.w;
        const bf16x8 b0 = *reinterpret_cast<const bf16x8*>(bp0 + k);
        const bf16x8 b1 = *reinterpret_cast<const bf16x8*>(bp1 + k);
        const bf16x8 b2 = *reinterpret_cast<const bf16x8*>(bp2 + k);
        const bf16x8 b3 = *reinterpret_cast<const bf16x8*>(bp3 + k);
        acc0 = __builtin_amdgcn_mfma_f32_16x16x32_bf16(af, b0, acc0, 0, 0, 0);
        acc1 = __builtin_amdgcn_mfma_f32_16x16x32_bf16(af, b1, acc1, 0, 0, 0);
        acc2 = __builtin_amdgcn_mfma_f32_16x16x32_bf16(af, b2, acc2, 0, 0, 0);
        acc3 = __builtin_amdgcn_mfma_f32_16x16x32_bf16(af, b3, acc3, 0, 0, 0);
    }

    // C/D layout: m = quad*4 + reg, n = l16 (HW-verified m89/m91)
    const size_t rbase = (size_t)(row0 + wave * 16 + quad * 4);
#pragma unroll
    for (int r = 0; r < 4; ++r) {
        float* crow = C + (rbase + r) * HH + l16;
        atomicAdd(crow +  0, acc0[r]);
        atomicAdd(crow + 16, acc1[r]);
        atomicAdd(crow + 32, acc2[r]);
        atomicAdd(crow + 48, acc3[r]);
    }
}

// ---------------------------------------------------------------------------
// LN epilogue: out = LayerNorm(relu(C + bias)) * gamma + beta (+ resid)
// block 256 -> 16 rows; grid 512
__global__ __launch_bounds__(256)
void k_ln(const float* __restrict__ C,
          const float* __restrict__ bias,
          const float* __restrict__ gamma,
          const float* __restrict__ beta,
          const float* __restrict__ resid,   // nullptr for layer 0
          float* __restrict__ out) {
    const int tid = threadIdx.x;
    const int row = tid >> 4;
    const int c0  = (tid & 15) * 4;
    const size_t grow = (size_t)(blockIdx.x * 16 + row);

    float4 v4 = *reinterpret_cast<const float4*>(&C[grow * HH + c0]);
    const float4 b4 = *reinterpret_cast<const float4*>(&bias[c0]);
    float v[4] = { fmaxf(v4.x + b4.x, 0.f), fmaxf(v4.y + b4.y, 0.f),
                   fmaxf(v4.z + b4.z, 0.f), fmaxf(v4.w + b4.w, 0.f) };
    float s = 0.f, ss = 0.f;
#pragma unroll
    for (int j = 0; j < 4; ++j) { s += v[j]; ss += v[j] * v[j]; }
#pragma unroll
    for (int m = 1; m < 16; m <<= 1) {
        s  += __shfl_xor(s,  m, 64);
        ss += __shfl_xor(ss, m, 64);
    }
    const float mean = s * (1.f / 64.f);
    const float var  = fmaxf(ss * (1.f / 64.f) - mean * mean, 0.f);
    const float inv  = rsqrtf(var + LN_EPS);
    const float4 g4  = *reinterpret_cast<const float4*>(&gamma[c0]);
    const float4 be4 = *reinterpret_cast<const float4*>(&beta[c0]);
    float4 o;
    o.x = (v[0] - mean) * inv * g4.x + be4.x;
    o.y = (v[1] - mean) * inv * g4.y + be4.y;
    o.z = (v[2] - mean) * inv * g4.z + be4.z;
    o.w = (v[3] - mean) * inv * g4.w + be4.w;
    if (resid) {
        const float4 r4 = *reinterpret_cast<const float4*>(&resid[grow * HH + c0]);
        o.x += r4.x; o.y += r4.y; o.z += r4.z; o.w += r4.w;
    }
    *reinterpret_cast<float4*>(&out[grow * HH + c0]) = o;
}

// ---------------------------------------------------------------------------
// K3: Zt1 = (h0 @ W1)^T  (bf16 [64][8192])   grid 2048 x 256
__global__ void k3_hw1(const float* __restrict__ h0,
                       const float* __restrict__ W1,
                       __hip_bfloat16* __restrict__ Zt1) {
    const int b = blockIdx.x, tid = threadIdx.x;
    const int lane = tid & 63;
    const int i = (b & 127) * 64 + lane;
    const int n = ((b >> 7) << 2) + (tid >> 6);
    float s = 0.f;
#pragma unroll 8
    for (int m = 0; m < HH; ++m)
        s += h0[(size_t)i * HH + m] * W1[m * HH + n];
    Zt1[(size_t)n * NN + i] = __float2bfloat16(s);
}

// ---------------------------------------------------------------------------
// K5: feat = h@Wf + bf ; attn = sigmoid(h@Wa + ba) ; g[I[i]] += feat*attn
// 4 nodes per block (one wave each).  grid 2048 x 256
__global__ __launch_bounds__(256)
void k5_pool(const float* __restrict__ h,
             const float* __restrict__ Wf, const float* __restrict__ bfv,
             const float* __restrict__ Wa, const float* __restrict__ bav,
             const int* __restrict__ I,
             float* __restrict__ g) {
    __shared__ float hrow[4][64];
    const int w = threadIdx.x >> 6, l = threadIdx.x & 63;
    const int node = blockIdx.x * 4 + w;
    hrow[w][l] = h[(size_t)node * HH + l];
    __syncthreads();
    float sf = bfv[l], sa = bav[l];
#pragma unroll 8
    for (int m = 0; m < HH; ++m) {
        const float hv = hrow[w][m];
        sf += hv * Wf[m * HH + l];
        sa += hv * Wa[m * HH + l];
    }
    const float attn = 1.f / (1.f + expf(-sa));
    atomicAdd(&g[(size_t)I[node] * HH + l], sf * attn);
}

// ---------------------------------------------------------------------------
// K6: zexp = exp(z - zmax[seg]); zsum[seg] += zexp; baryn[seg] += zexp * xyz
// grid 32 x 256
__global__ void k6_bary(const float* __restrict__ X,
                        const int* __restrict__ I,
                        const float* __restrict__ zarr,
                        const float* __restrict__ zmax,
                        float* __restrict__ zsum,
                        float* __restrict__ baryn) {
    const int i = blockIdx.x * 256 + threadIdx.x;
    const int seg = I[i];
    const float ze = expf(zarr[i] - zmax[seg]);
    atomicAdd(&zsum[seg], ze);
    atomicAdd(&baryn[seg * 3 + 0], ze * X[i * FF + 13]);
    atomicAdd(&baryn[seg * 3 + 1], ze * X[i * FF + 14]);
    atomicAdd(&baryn[seg * 3 + 2], ze * X[i * FF + 15]);
}

// ---------------------------------------------------------------------------
// K7: out[gi] = concat(g[gi], baryn[gi]/zsum[gi]) @ Wout + bout
// one wave per graph; grid 64 x 256. Output fp32.
__global__ void k7_out(const float* __restrict__ g,
                       const float* __restrict__ zsum,
                       const float* __restrict__ baryn,
                       const float* __restrict__ Wout,
                       const float* __restrict__ bout,
                       float* __restrict__ out) {
    const int w = threadIdx.x >> 6, lane = threadIdx.x & 63;
    const int gi = blockIdx.x * 4 + w;
    const float vg = g[(size_t)gi * HH + lane];
    const float zs = zsum[gi];
    const float invz = (zs > 0.f) ? (1.f / zs) : 0.f;
    const float extra = (lane < 3) ? baryn[gi * 3 + lane] * invz : 0.f;
#pragma unroll
    for (int d = 0; d < 3; ++d) {
        float p = vg * Wout[lane * 3 + d];
        if (lane < 3) p += extra * Wout[(64 + lane) * 3 + d];
#pragma unroll
        for (int m = 1; m < 64; m <<= 1) p += __shfl_xor(p, m, 64);
        if (lane == 0) out[gi * 3 + d] = p + bout[d];
    }
}

// ---------------------------------------------------------------------------
extern "C" void kernel_launch(void* const* d_in, const int* in_sizes, int n_in,
                              void* d_out, int out_size, void* d_ws, size_t ws_size,
                              hipStream_t stream) {
    const float* X   = (const float*)d_in[0];
    const float* A   = (const float*)d_in[1];
    const int*   I   = (const int*)d_in[2];
    const float* W0  = (const float*)d_in[3];
    const float* b0  = (const float*)d_in[4];
    const float* g0  = (const float*)d_in[5];
    const float* be0 = (const float*)d_in[6];
    const float* W1  = (const float*)d_in[7];
    const float* b1  = (const float*)d_in[8];
    const float* g1  = (const float*)d_in[9];
    const float* be1 = (const float*)d_in[10];
    const float* Wf  = (const float*)d_in[11];
    const float* bfv = (const float*)d_in[12];
    const float* Wa  = (const float*)d_in[13];
    const float* bav = (const float*)d_in[14];
    const float* Wo  = (const float*)d_in[15];
    const float* bo  = (const float*)d_in[16];

    char* ws = (char*)d_ws;
    // [C0 2MB][C1 2MB][accr ~69KB] -- one contiguous memset region at offset 0
    float* C0   = (float*)(ws);
    float* C1   = (float*)(ws + (2u << 20));
    float* accr = (float*)(ws + (4u << 20));
    float* g     = accr;                 // 256*64
    float* zmax  = accr + GG * HH;       // 256
    float* zsum  = zmax + GG;            // 256
    float* baryn = zsum + GG;            // 256*3
    const size_t memset_bytes = (size_t)(2 * NN * HH + GG * HH + GG + GG + GG * 3) * sizeof(float);

    __hip_bfloat16* Zt0 = (__hip_bfloat16*)(ws + (4u << 20) + (128u << 10));  // 1 MiB
    __hip_bfloat16* Zt1 = (__hip_bfloat16*)(ws + (5u << 20) + (128u << 10));  // 1 MiB
    float* h0   = (float*)(ws + (6u << 20) + (128u << 10));                   // 2 MiB
    float* h    = (float*)(ws + (8u << 20) + (128u << 10));                   // 2 MiB
    float* zarr = (float*)(ws + (10u << 20) + (128u << 10));                  // 32 KiB

    hipMemsetAsync(ws, 0, memset_bytes, stream);

    k1_xw0<<<2048, 256, 0, stream>>>(X, W0, I, Zt0, zarr, (unsigned int*)zmax);
    k_gemm_split<<<1024, 256, 0, stream>>>(A, Zt0, C0);
    k_ln<<<512, 256, 0, stream>>>(C0, b0, g0, be0, nullptr, h0);
    k3_hw1<<<2048, 256, 0, stream>>>(h0, W1, Zt1);
    k_gemm_split<<<1024, 256, 0, stream>>>(A, Zt1, C1);
    k_ln<<<512, 256, 0, stream>>>(C1, b1, g1, be1, h0, h);
    k5_pool<<<2048, 256, 0, stream>>>(h, Wf, bfv, Wa, bav, I, g);
    k6_bary<<<32, 256, 0, stream>>>(X, I, zarr, zmax, zsum, baryn);
    k7_out<<<64, 256, 0, stream>>>(g, zsum, baryn, Wo, bo, (float*)d_out);
}